// Round 9
// baseline (539.366 us; speedup 1.0000x reference)
//
#include <hip/hip_runtime.h>
#include <hip/hip_bf16.h>
#include <cstdint>
#include <cstddef>

#define D_DIM 128
#define NEG_LOG2E (-1.44269504f)

typedef __attribute__((ext_vector_type(8))) short short8;
typedef __attribute__((ext_vector_type(4))) float f32x4;

__device__ __forceinline__ float sigmoid_fast(float z) {
  return __builtin_amdgcn_rcpf(1.0f + __expf(-z));
}

__device__ __forceinline__ unsigned short f2bf(float f) {
  union { float f; unsigned u; } v; v.f = f;
  unsigned r = v.u + 0x7FFF + ((v.u >> 16) & 1);   // RNE
  return (unsigned short)(r >> 16);
}
__device__ __forceinline__ float bf_lo(unsigned u) { return __uint_as_float(u << 16); }
__device__ __forceinline__ float bf_hi(unsigned u) { return __uint_as_float(u & 0xFFFF0000u); }

// k1: wconv (blocks 0..95) + per-dst histogram (all blocks, int4, global atomics).
__global__ __launch_bounds__(256) void wconv_hist_kernel(
    const float* __restrict__ s0, const float* __restrict__ s1, const float* __restrict__ s2,
    const float* __restrict__ s3, const float* __restrict__ s4, const float* __restrict__ s5,
    short* __restrict__ wdst,
    const int* __restrict__ dst_dt, const int* __restrict__ dst_td,
    int* __restrict__ cnt, int n_task, int E) {
  int t = threadIdx.x;
  if (blockIdx.x < 96) {
    int idx = blockIdx.x * 256 + t;
    int mat = idx >> 12;
    int pos = (idx & 4095) * 4;
    const float* s = (mat == 0) ? s0 : (mat == 1) ? s1 : (mat == 2) ? s2
                   : (mat == 3) ? s3 : (mat == 4) ? s4 : s5;
    float4 f = *(const float4*)(s + pos);
    short4 o;
    o.x = (short)f2bf(f.x); o.y = (short)f2bf(f.y);
    o.z = (short)f2bf(f.z); o.w = (short)f2bf(f.w);
    *(short4*)(wdst + mat * 16384 + pos) = o;
  }
  int E4 = E >> 2;
  int i = blockIdx.x * 256 + t;
  if (i < E4) {
    int4 a = *(const int4*)(dst_dt + 4 * i);
    atomicAdd(&cnt[a.x], 1); atomicAdd(&cnt[a.y], 1);
    atomicAdd(&cnt[a.z], 1); atomicAdd(&cnt[a.w], 1);
    int4 b = *(const int4*)(dst_td + 4 * i);
    atomicAdd(&cnt[n_task + b.x], 1); atomicAdd(&cnt[n_task + b.y], 1);
    atomicAdd(&cnt[n_task + b.z], 1); atomicAdd(&cnt[n_task + b.w], 1);
  }
  if (blockIdx.x == 0 && t < (E & 3)) {
    int j = (E & ~3) + t;
    atomicAdd(&cnt[dst_dt[j]], 1);
    atomicAdd(&cnt[n_task + dst_td[j]], 1);
  }
}

// k2: per-256-bin block sums.
__global__ __launch_bounds__(256) void scan_p1_kernel(
    const int* __restrict__ cnt, int* __restrict__ bsum, int n_tot) {
  __shared__ int red[256];
  int t = threadIdx.x;
  int idx = blockIdx.x * 256 + t;
  red[t] = (idx < n_tot) ? cnt[idx] : 0;
  __syncthreads();
  for (int s = 128; s > 0; s >>= 1) {
    if (t < s) red[t] += red[t + s];
    __syncthreads();
  }
  if (t == 0) bsum[blockIdx.x] = red[0];
}

// k3: scan of block sums (<=512); writes total sentinel into offs[n_tot].
__global__ __launch_bounds__(512) void scan_p2_kernel(
    const int* __restrict__ bsum, int* __restrict__ bpre,
    int* __restrict__ offs, int SB, int n_tot) {
  __shared__ int sc[512];
  int t = threadIdx.x;
  int v = (t < SB) ? bsum[t] : 0;
  sc[t] = v; __syncthreads();
  for (int s = 1; s < 512; s <<= 1) {
    int u = (t >= s) ? sc[t - s] : 0;
    __syncthreads(); sc[t] += u; __syncthreads();
  }
  if (t < SB) bpre[t] = sc[t] - v;
  if (t == 511) offs[n_tot] = sc[511];
}

// k4: final per-dst exclusive offsets.
__global__ __launch_bounds__(256) void scan_p3_kernel(
    const int* __restrict__ cnt, const int* __restrict__ bpre,
    int* __restrict__ offs, int n_tot) {
  __shared__ int sc[256];
  int t = threadIdx.x;
  int idx = blockIdx.x * 256 + t;
  int v = (idx < n_tot) ? cnt[idx] : 0;
  sc[t] = v; __syncthreads();
  for (int s = 1; s < 256; s <<= 1) {
    int u = (t >= s) ? sc[t - s] : 0;
    __syncthreads(); sc[t] += u; __syncthreads();
  }
  if (idx < n_tot) offs[idx] = bpre[blockIdx.x] + sc[t] - v;
}

// k5: bucket base/cursor setup. Buckets: task b<nbt start=b*256; data start=n_task+(b-nbt)*256.
__global__ __launch_bounds__(256) void bucket_setup_kernel(
    const int* __restrict__ offs, int* __restrict__ bbase, int* __restrict__ bcur,
    int nbt, int NB, int n_task, int n_tot) {
  int b = blockIdx.x * 256 + threadIdx.x;
  if (b < NB) {
    int s = (b < nbt) ? (b << 8) : n_task + ((b - nbt) << 8);
    int v = offs[s];
    bbase[b] = v; bcur[b] = v;
  } else if (b == NB) {
    bbase[NB] = offs[n_tot];
  }
}

// Per-node MFMA precompute for BOTH node types in one launch.
// G channel of YG is pre-scaled by -log2e so gather's sigmoid uses exp2 directly.
__global__ __launch_bounds__(256) void node_mfma_all(
    const float* __restrict__ x_data, const float* __restrict__ x_task,
    const short* __restrict__ Wb,
    const float* __restrict__ bmn_dt, const float* __restrict__ bme_dt,
    const float* __restrict__ bgn_dt, const float* __restrict__ bge_dt,
    const float* __restrict__ bmn_td, const float* __restrict__ bme_td,
    const float* __restrict__ bgn_td, const float* __restrict__ bge_td,
    const float* __restrict__ bs_data, const float* __restrict__ bs_task,
    const float* __restrict__ bias_dt, const float* __restrict__ bias_td,
    unsigned int* __restrict__ YG_dt, unsigned int* __restrict__ YG_td,
    float* __restrict__ out, int n_data, int n_task, int gd) {
  __shared__ unsigned sh[32][132];
  const bool is_data = (int)blockIdx.x < gd;
  const float* x; const short *Wmnb, *Wgnb, *Wsb;
  const float *bmn, *bme, *bgn, *bge, *bs, *bias_other;
  unsigned* YG; float* out_init; int n, bid;
  if (is_data) {
    x = x_data; Wmnb = Wb; Wgnb = Wb + 16384; Wsb = Wb + 32768;
    bmn = bmn_dt; bme = bme_dt; bgn = bgn_dt; bge = bge_dt;
    bs = bs_data; bias_other = bias_td;
    YG = YG_dt; out_init = out; n = n_data; bid = blockIdx.x;
  } else {
    x = x_task; Wmnb = Wb + 3 * 16384; Wgnb = Wb + 4 * 16384; Wsb = Wb + 5 * 16384;
    bmn = bmn_td; bme = bme_td; bgn = bgn_td; bge = bge_td;
    bs = bs_task; bias_other = bias_dt;
    YG = YG_td; out_init = out + (size_t)n_data * D_DIM; n = n_task; bid = blockIdx.x - gd;
  }
  const int t = threadIdx.x;
  const int wave = t >> 6, lane = t & 63;
  const int q = lane >> 4, l15 = lane & 15;
  const int ng = wave >> 1;
  const int h = (wave & 1) * 64;
  const int base_node = bid * 32;
  const int node_base = base_node + ng * 16;

  short8 a[4];
  {
    int m = node_base + l15;
    int mc = m < n ? m : (n - 1);
    const float* xrow = x + (size_t)mc * D_DIM;
#pragma unroll
    for (int ks = 0; ks < 4; ++ks) {
      float4 f0 = *(const float4*)(xrow + ks * 32 + q * 8);
      float4 f1 = *(const float4*)(xrow + ks * 32 + q * 8 + 4);
      union { short8 s; __hip_bfloat162 hh[4]; } u;
      u.hh[0] = __float22bfloat162_rn({f0.x, f0.y});
      u.hh[1] = __float22bfloat162_rn({f0.z, f0.w});
      u.hh[2] = __float22bfloat162_rn({f1.x, f1.y});
      u.hh[3] = __float22bfloat162_rn({f1.z, f1.w});
      a[ks] = u.s;
    }
  }

  f32x4 accY[4], accG[4], accS[4];
#pragma unroll
  for (int nt = 0; nt < 4; ++nt) { accY[nt] = {0,0,0,0}; accG[nt] = {0,0,0,0}; accS[nt] = {0,0,0,0}; }

#pragma unroll
  for (int nt = 0; nt < 4; ++nt) {
    const int row = h + nt * 16 + l15;
#pragma unroll
    for (int ks = 0; ks < 4; ++ks) {
      const int off = row * D_DIM + ks * 32 + q * 8;
      short8 bm  = *(const short8*)(Wmnb + off);
      short8 bg  = *(const short8*)(Wgnb + off);
      short8 bsw = *(const short8*)(Wsb + off);
      accY[nt] = __builtin_amdgcn_mfma_f32_16x16x32_bf16(a[ks], bm,  accY[nt], 0, 0, 0);
      accG[nt] = __builtin_amdgcn_mfma_f32_16x16x32_bf16(a[ks], bg,  accG[nt], 0, 0, 0);
      accS[nt] = __builtin_amdgcn_mfma_f32_16x16x32_bf16(a[ks], bsw, accS[nt], 0, 0, 0);
    }
  }

#pragma unroll
  for (int nt = 0; nt < 4; ++nt) {
    int d = h + nt * 16 + l15;
    float bmv = bmn[d] + bme[d];
    float bgv = bgn[d] + bge[d];
#pragma unroll
    for (int r = 0; r < 4; ++r) {
      union { __hip_bfloat162 hh; unsigned u; } pck;
      pck.hh = __float22bfloat162_rn({accY[nt][r] + bmv,
                                      (accG[nt][r] + bgv) * NEG_LOG2E});
      sh[ng * 16 + q * 4 + r][d] = pck.u;
    }
  }
  __syncthreads();
#pragma unroll
  for (int it = 0; it < 4; ++it) {
    int idx = (it * 256 + t) * 4;
    int nl = idx >> 7, dd = idx & 127;
    int node = base_node + nl;
    if (node < n)
      *(uint4*)(YG + (size_t)node * D_DIM + dd) = *(const uint4*)&sh[nl][dd];
  }
  __syncthreads();

  float* shf = (float*)sh;
#pragma unroll
  for (int nt = 0; nt < 4; ++nt) {
    int d = h + nt * 16 + l15;
    float bsv = bs[d];
#pragma unroll
    for (int r = 0; r < 4; ++r)
      shf[(ng * 16 + q * 4 + r) * 132 + d] = sigmoid_fast(accS[nt][r] + bsv) + 0.5f;
  }
  __syncthreads();
#pragma unroll
  for (int it = 0; it < 4; ++it) {
    int idx = (it * 256 + t) * 4;
    int nl = idx >> 7, dd = idx & 127;
    int node = base_node + nl;
    if (node < n) {
      float4 xv = *(const float4*)(x + (size_t)node * D_DIM + dd);
      float4 bo = *(const float4*)(bias_other + dd);
      const float* sp = &shf[nl * 132 + dd];
      float4 o;
      o.x = sp[0] * xv.x + bo.x;
      o.y = sp[1] * xv.y + bo.y;
      o.z = sp[2] * xv.z + bo.z;
      o.w = sp[3] * xv.w + bo.w;
      *(float4*)(out_init + (size_t)node * D_DIM + dd) = o;
    }
  }
}

// Pass A: coarse partition, int4-vectorized. 256-dst buckets for both types.
// Entry = {src, ef_hi24|loc8}.
__global__ __launch_bounds__(256) void sort_a_kernel(
    const int* __restrict__ src_dt, const int* __restrict__ dst_dt, const float* __restrict__ ef_dt,
    const int* __restrict__ src_td, const int* __restrict__ dst_td, const float* __restrict__ ef_td,
    int* __restrict__ bcur, int2* __restrict__ eA, int nbt, int NB, int E) {
  __shared__ int lh[512];
  __shared__ int lcur[512];
  int t = threadIdx.x;
  lh[t] = 0; lh[t + 256] = 0;
  __syncthreads();
  int e0 = blockIdx.x * 4096;
  int e1 = min(E, e0 + 4096);
  const bool full = (e1 - e0 == 4096);
  if (full) {
#pragma unroll
    for (int k = 0; k < 4; ++k) {
      int b4 = e0 + (k * 256 + t) * 4;
      int4 d = *(const int4*)(dst_dt + b4);
      atomicAdd(&lh[d.x >> 8], 1); atomicAdd(&lh[d.y >> 8], 1);
      atomicAdd(&lh[d.z >> 8], 1); atomicAdd(&lh[d.w >> 8], 1);
      int4 d2 = *(const int4*)(dst_td + b4);
      atomicAdd(&lh[nbt + (d2.x >> 8)], 1); atomicAdd(&lh[nbt + (d2.y >> 8)], 1);
      atomicAdd(&lh[nbt + (d2.z >> 8)], 1); atomicAdd(&lh[nbt + (d2.w >> 8)], 1);
    }
  } else {
    for (int i = e0 + t; i < e1; i += 256) {
      atomicAdd(&lh[dst_dt[i] >> 8], 1);
      atomicAdd(&lh[nbt + (dst_td[i] >> 8)], 1);
    }
  }
  __syncthreads();
#pragma unroll
  for (int k = 0; k < 2; ++k) {
    int b = t + k * 256;
    int c = lh[b];
    if (b < NB && c) lcur[b] = atomicAdd(&bcur[b], c);
  }
  __syncthreads();
#define PUT_DT(ss, dd, ff) do { \
    int pos = atomicAdd(&lcur[(dd) >> 8], 1); \
    eA[pos] = make_int2((ss), (int)((__float_as_uint(ff) & 0xFFFFFF00u) | (unsigned)((dd) & 255))); \
  } while (0)
#define PUT_TD(ss, dd, ff) do { \
    int pos = atomicAdd(&lcur[nbt + ((dd) >> 8)], 1); \
    eA[pos] = make_int2((ss), (int)((__float_as_uint(ff) & 0xFFFFFF00u) | (unsigned)((dd) & 255))); \
  } while (0)
  if (full) {
#pragma unroll
    for (int k = 0; k < 4; ++k) {
      int b4 = e0 + (k * 256 + t) * 4;
      int4 s = *(const int4*)(src_dt + b4);
      int4 d = *(const int4*)(dst_dt + b4);
      float4 f = *(const float4*)(ef_dt + b4);
      PUT_DT(s.x, d.x, f.x); PUT_DT(s.y, d.y, f.y);
      PUT_DT(s.z, d.z, f.z); PUT_DT(s.w, d.w, f.w);
      s = *(const int4*)(src_td + b4);
      d = *(const int4*)(dst_td + b4);
      f = *(const float4*)(ef_td + b4);
      PUT_TD(s.x, d.x, f.x); PUT_TD(s.y, d.y, f.y);
      PUT_TD(s.z, d.z, f.z); PUT_TD(s.w, d.w, f.w);
    }
  } else {
    for (int i = e0 + t; i < e1; i += 256) {
      PUT_DT(src_dt[i], dst_dt[i], ef_dt[i]);
      PUT_TD(src_td[i], dst_td[i], ef_td[i]);
    }
  }
#undef PUT_DT
#undef PUT_TD
}

// Pass B (lite): one block per bucket, SINGLE pass. lcur preloaded from the
// global per-dst offsets; scatter entries to final positions; pre-shift src<<7
// so gather addressing is add-only.
__global__ __launch_bounds__(256) void sort_b_kernel(
    const int2* __restrict__ eA, const int* __restrict__ bbase,
    const int* __restrict__ offs, int2* __restrict__ eB,
    int nbt, int n_task, int n_tot) {
  __shared__ int lcur[256];
  int b = blockIdx.x, t = threadIdx.x;
  int base = bbase[b];
  int end = bbase[b + 1];
  int c0, nloc;
  if (b < nbt) { c0 = b << 8; nloc = min(256, n_task - c0); }
  else { c0 = n_task + ((b - nbt) << 8); nloc = min(256, n_tot - c0); }
  if (t < nloc) lcur[t] = offs[c0 + t];
  __syncthreads();
  for (int i = base + t; i < end; i += 256) {
    int2 e = eA[i];
    int pos = atomicAdd(&lcur[((unsigned)e.y) & 255u], 1);
    eB[pos] = make_int2(e.x << 7, e.y);
  }
}

// Combined gather. Wave w<n_task -> task dst (dt conv), else data dst.
// eB.x is pre-shifted src*128; G channel pre-scaled by -log2e.
__device__ __forceinline__ void gs(float2& acc, int2 e, uint2 yv,
                                   float2 wme, float2 wge2) {
  float f = __int_as_float(e.y & (int)0xFFFFFF00);
  float g0 = __builtin_amdgcn_rcpf(1.0f + __builtin_amdgcn_exp2f(fmaf(f, wge2.x, bf_hi(yv.x)))) - 0.5f;
  float g1 = __builtin_amdgcn_rcpf(1.0f + __builtin_amdgcn_exp2f(fmaf(f, wge2.y, bf_hi(yv.y)))) - 0.5f;
  acc.x = fmaf(fmaf(f, wme.x, bf_lo(yv.x)), g0, acc.x);
  acc.y = fmaf(fmaf(f, wme.y, bf_lo(yv.y)), g1, acc.y);
}

__global__ __launch_bounds__(256) void gather_kernel(
    const unsigned* __restrict__ YG_dt, const unsigned* __restrict__ YG_td,
    const int* __restrict__ offsets, const int2* __restrict__ edata,
    const float* __restrict__ Wme_dt, const float* __restrict__ Wge_dt,
    const float* __restrict__ Wme_td, const float* __restrict__ Wge_td,
    float* __restrict__ out, int n_task, int n_data) {
  int w = (int)((blockIdx.x * 256u + threadIdx.x) >> 6);
  int lane = threadIdx.x & 63;
  if (w >= n_task + n_data) return;
  bool is_dt = w < n_task;
  const unsigned* YG = is_dt ? YG_dt : YG_td;
  const float* Wme = is_dt ? Wme_dt : Wme_td;
  const float* Wge = is_dt ? Wge_dt : Wge_td;
  size_t orow = is_dt ? (size_t)(n_data + w) : (size_t)(w - n_task);
  int beg = __builtin_amdgcn_readfirstlane(offsets[w]);
  int end = __builtin_amdgcn_readfirstlane(offsets[w + 1]);
  float2 wme = *(const float2*)(Wme + 2 * lane);
  float2 wge = *(const float2*)(Wge + 2 * lane);
  float2 wge2 = {wge.x * NEG_LOG2E, wge.y * NEG_LOG2E};
  const unsigned* YGl = YG + 2 * lane;
  float* op = out + orow * D_DIM + 2 * lane;
  float2 acc0 = *(const float2*)op;
  float2 acc1 = {0.0f, 0.0f};
  int p = beg;
  for (; p + 8 <= end; p += 8) {
    int2 e0 = edata[p],     e1 = edata[p + 1], e2 = edata[p + 2], e3 = edata[p + 3];
    int2 e4 = edata[p + 4], e5 = edata[p + 5], e6 = edata[p + 6], e7 = edata[p + 7];
    gs(acc0, e0, *(const uint2*)(YGl + e0.x), wme, wge2);
    gs(acc1, e1, *(const uint2*)(YGl + e1.x), wme, wge2);
    gs(acc0, e2, *(const uint2*)(YGl + e2.x), wme, wge2);
    gs(acc1, e3, *(const uint2*)(YGl + e3.x), wme, wge2);
    gs(acc0, e4, *(const uint2*)(YGl + e4.x), wme, wge2);
    gs(acc1, e5, *(const uint2*)(YGl + e5.x), wme, wge2);
    gs(acc0, e6, *(const uint2*)(YGl + e6.x), wme, wge2);
    gs(acc1, e7, *(const uint2*)(YGl + e7.x), wme, wge2);
  }
  for (; p + 2 <= end; p += 2) {
    int2 e0 = edata[p], e1 = edata[p + 1];
    gs(acc0, e0, *(const uint2*)(YGl + e0.x), wme, wge2);
    gs(acc1, e1, *(const uint2*)(YGl + e1.x), wme, wge2);
  }
  if (p < end) {
    int2 e0 = edata[p];
    gs(acc0, e0, *(const uint2*)(YGl + e0.x), wme, wge2);
  }
  acc0.x = fmaxf(acc0.x + acc1.x, 0.0f);
  acc0.y = fmaxf(acc0.y + acc1.y, 0.0f);
  *(float2*)op = acc0;
}

extern "C" void kernel_launch(void* const* d_in, const int* in_sizes, int n_in,
                              void* d_out, int out_size, void* d_ws, size_t ws_size,
                              hipStream_t stream) {
  const float* x_data  = (const float*)d_in[0];
  const float* x_task  = (const float*)d_in[1];
  const int*   src_dt  = (const int*)d_in[2];
  const int*   dst_dt  = (const int*)d_in[3];
  const float* ef_dt   = (const float*)d_in[4];
  const int*   src_td  = (const int*)d_in[5];
  const int*   dst_td  = (const int*)d_in[6];
  const float* ef_td   = (const float*)d_in[7];
  const float* Wmn_dt  = (const float*)d_in[8];
  const float* bmn_dt  = (const float*)d_in[9];
  const float* Wme_dt  = (const float*)d_in[10];
  const float* bme_dt  = (const float*)d_in[11];
  const float* Wgn_dt  = (const float*)d_in[12];
  const float* bgn_dt  = (const float*)d_in[13];
  const float* Wge_dt  = (const float*)d_in[14];
  const float* bge_dt  = (const float*)d_in[15];
  const float* bias_dt = (const float*)d_in[16];
  const float* Wmn_td  = (const float*)d_in[17];
  const float* bmn_td  = (const float*)d_in[18];
  const float* Wme_td  = (const float*)d_in[19];
  const float* bme_td  = (const float*)d_in[20];
  const float* Wgn_td  = (const float*)d_in[21];
  const float* bgn_td  = (const float*)d_in[22];
  const float* Wge_td  = (const float*)d_in[23];
  const float* bge_td  = (const float*)d_in[24];
  const float* bias_td = (const float*)d_in[25];
  const float* Ws_data = (const float*)d_in[26];
  const float* bs_data = (const float*)d_in[27];
  const float* Ws_task = (const float*)d_in[28];
  const float* bs_task = (const float*)d_in[29];
  float* out = (float*)d_out;

  const int N_DATA = in_sizes[0] / D_DIM;   // 100000
  const int N_TASK = in_sizes[1] / D_DIM;   // 20000
  const int E = in_sizes[2];                // 1000000
  const int N_TOT = N_TASK + N_DATA;        // 120000
  const int SB = (N_TOT + 255) / 256;       // 469 (<=512)
  const int NBT = (N_TASK + 255) >> 8;      // 79 task buckets (256 dsts each)
  const int NBD = (N_DATA + 255) >> 8;      // 391 data buckets
  const int NB = NBT + NBD;                 // 470
  const int GD = (N_DATA + 31) / 32;
  const int GT = (N_TASK + 31) / 32;

  char* ws = (char*)d_ws;
  size_t off = 0;
  auto alloc = [&](size_t bytes) { void* p = ws + off; off += (bytes + 255) & ~(size_t)255; return p; };
  unsigned int* YG_dt = (unsigned int*)alloc((size_t)N_DATA * D_DIM * 4);
  unsigned int* YG_td = (unsigned int*)alloc((size_t)N_TASK * D_DIM * 4);
  int2* eA    = (int2*)alloc((size_t)2 * E * 8);
  int2* eB    = (int2*)alloc((size_t)2 * E * 8);
  int*  offs  = (int*)alloc((size_t)(N_TOT + 1) * 4);
  int*  cnt   = (int*)alloc((size_t)N_TOT * 4);
  int*  bsum  = (int*)alloc(512 * 4);
  int*  bpre  = (int*)alloc(512 * 4);
  int*  bbase = (int*)alloc(512 * 4);
  int*  bcur  = (int*)alloc(512 * 4);
  short* Wb   = (short*)alloc((size_t)6 * 16384 * 2);
  (void)ws_size; (void)n_in; (void)out_size;

  hipMemsetAsync(cnt, 0, (size_t)N_TOT * 4, stream);

  wconv_hist_kernel<<<1024, 256, 0, stream>>>(
      Wmn_dt, Wgn_dt, Ws_data, Wmn_td, Wgn_td, Ws_task, Wb,
      dst_dt, dst_td, cnt, N_TASK, E);

  scan_p1_kernel<<<SB, 256, 0, stream>>>(cnt, bsum, N_TOT);
  scan_p2_kernel<<<1, 512, 0, stream>>>(bsum, bpre, offs, SB, N_TOT);
  scan_p3_kernel<<<SB, 256, 0, stream>>>(cnt, bpre, offs, N_TOT);
  bucket_setup_kernel<<<2, 256, 0, stream>>>(offs, bbase, bcur, NBT, NB, N_TASK, N_TOT);

  node_mfma_all<<<GD + GT, 256, 0, stream>>>(
      x_data, x_task, Wb,
      bmn_dt, bme_dt, bgn_dt, bge_dt,
      bmn_td, bme_td, bgn_td, bge_td,
      bs_data, bs_task, bias_dt, bias_td,
      YG_dt, YG_td, out, N_DATA, N_TASK, GD);

  sort_a_kernel<<<(E + 4095) / 4096, 256, 0, stream>>>(
      src_dt, dst_dt, ef_dt, src_td, dst_td, ef_td, bcur, eA, NBT, NB, E);
  sort_b_kernel<<<NB, 256, 0, stream>>>(eA, bbase, offs, eB, NBT, N_TASK, N_TOT);

  gather_kernel<<<(N_TOT + 3) / 4, 256, 0, stream>>>(
      YG_dt, YG_td, offs, eB, Wme_dt, Wge_dt, Wme_td, Wge_td, out, N_TASK, N_DATA);
}

// Round 10
// 475.181 us; speedup vs baseline: 1.1351x; 1.1351x over previous
//
#include <hip/hip_runtime.h>
#include <hip/hip_bf16.h>
#include <cstdint>
#include <cstddef>

#define D_DIM 128
#define NEG_LOG2E (-1.44269504f)

typedef __attribute__((ext_vector_type(8))) short short8;
typedef __attribute__((ext_vector_type(4))) float f32x4;

__device__ __forceinline__ float sigmoid_fast(float z) {
  return __builtin_amdgcn_rcpf(1.0f + __expf(-z));
}

__device__ __forceinline__ unsigned short f2bf(float f) {
  union { float f; unsigned u; } v; v.f = f;
  unsigned r = v.u + 0x7FFF + ((v.u >> 16) & 1);   // RNE
  return (unsigned short)(r >> 16);
}
__device__ __forceinline__ float bf_lo(unsigned u) { return __uint_as_float(u << 16); }
__device__ __forceinline__ float bf_hi(unsigned u) { return __uint_as_float(u & 0xFFFF0000u); }

// Fused: wconv (blocks 0..95) + coarse histogram (all blocks, int4-vectorized)
// + bucket scan (by the last block to finish, device-scope done-counter).
// Buckets: task 64 dsts (nbt), data 256 dsts.
__global__ __launch_bounds__(256) void fused_pre_kernel(
    const float* __restrict__ s0, const float* __restrict__ s1, const float* __restrict__ s2,
    const float* __restrict__ s3, const float* __restrict__ s4, const float* __restrict__ s5,
    short* __restrict__ wdst,
    const int* __restrict__ dst_dt, const int* __restrict__ dst_td,
    int* __restrict__ ghist, int* __restrict__ done,
    int* __restrict__ bbase, int* __restrict__ bcur, int* __restrict__ offsets,
    int nbt, int NB, int E, int n_tot) {
  __shared__ int lh[768];
  __shared__ int sc[256];
  __shared__ int lastflag;
  int t = threadIdx.x;

  // --- weight bf16 conversion (6 x 128x128 matrices) ---
  if (blockIdx.x < 96) {
    int idx = blockIdx.x * 256 + t;
    int mat = idx >> 12;
    int pos = (idx & 4095) * 4;
    const float* s = (mat == 0) ? s0 : (mat == 1) ? s1 : (mat == 2) ? s2
                   : (mat == 3) ? s3 : (mat == 4) ? s4 : s5;
    float4 f = *(const float4*)(s + pos);
    short4 o;
    o.x = (short)f2bf(f.x); o.y = (short)f2bf(f.y);
    o.z = (short)f2bf(f.z); o.w = (short)f2bf(f.w);
    *(short4*)(wdst + mat * 16384 + pos) = o;
  }

  // --- coarse histogram with LDS pre-aggregation (int4 loads) ---
  lh[t] = 0; lh[t + 256] = 0; lh[t + 512] = 0;
  __syncthreads();
  int E4 = E >> 2;
  for (int i = blockIdx.x * 256 + t; i < E4; i += gridDim.x * 256) {
    int4 a = *(const int4*)(dst_dt + 4 * i);
    atomicAdd(&lh[a.x >> 6], 1); atomicAdd(&lh[a.y >> 6], 1);
    atomicAdd(&lh[a.z >> 6], 1); atomicAdd(&lh[a.w >> 6], 1);
    int4 b = *(const int4*)(dst_td + 4 * i);
    atomicAdd(&lh[nbt + (b.x >> 8)], 1); atomicAdd(&lh[nbt + (b.y >> 8)], 1);
    atomicAdd(&lh[nbt + (b.z >> 8)], 1); atomicAdd(&lh[nbt + (b.w >> 8)], 1);
  }
  if (blockIdx.x == 0 && t < (E & 3)) {
    int j = (E & ~3) + t;
    atomicAdd(&lh[dst_dt[j] >> 6], 1);
    atomicAdd(&lh[nbt + (dst_td[j] >> 8)], 1);
  }
  __syncthreads();
#pragma unroll
  for (int k = 0; k < 3; ++k) {
    int b = t + k * 256;
    int c = lh[b];
    if (b < NB && c) atomicAdd(&ghist[b], c);
  }
  __threadfence();
  __syncthreads();
  if (t == 0) {
    int prev = atomicAdd(done, 1);
    lastflag = (prev == (int)gridDim.x - 1);
  }
  __syncthreads();
  if (!lastflag) return;
  __threadfence();

  // --- bucket scan (single block) ---
  int i0 = t * 3;
  int c0 = (i0     < NB) ? atomicAdd(&ghist[i0],     0) : 0;
  int c1 = (i0 + 1 < NB) ? atomicAdd(&ghist[i0 + 1], 0) : 0;
  int c2 = (i0 + 2 < NB) ? atomicAdd(&ghist[i0 + 2], 0) : 0;
  int tot = c0 + c1 + c2;
  sc[t] = tot; __syncthreads();
  for (int s = 1; s < 256; s <<= 1) {
    int u = (t >= s) ? sc[t - s] : 0;
    __syncthreads(); sc[t] += u; __syncthreads();
  }
  int base = sc[t] - tot;
  if (i0     < NB) { bbase[i0]     = base;           bcur[i0]     = base; }
  if (i0 + 1 < NB) { bbase[i0 + 1] = base + c0;      bcur[i0 + 1] = base + c0; }
  if (i0 + 2 < NB) { bbase[i0 + 2] = base + c0 + c1; bcur[i0 + 2] = base + c0 + c1; }
  if (t == 255) { bbase[NB] = sc[255]; offsets[n_tot] = sc[255]; }
}

// Per-node MFMA precompute for BOTH node types in one launch.
// G channel of YG is pre-scaled by -log2e so gather's sigmoid uses exp2 directly.
__global__ __launch_bounds__(256) void node_mfma_all(
    const float* __restrict__ x_data, const float* __restrict__ x_task,
    const short* __restrict__ Wb,
    const float* __restrict__ bmn_dt, const float* __restrict__ bme_dt,
    const float* __restrict__ bgn_dt, const float* __restrict__ bge_dt,
    const float* __restrict__ bmn_td, const float* __restrict__ bme_td,
    const float* __restrict__ bgn_td, const float* __restrict__ bge_td,
    const float* __restrict__ bs_data, const float* __restrict__ bs_task,
    const float* __restrict__ bias_dt, const float* __restrict__ bias_td,
    unsigned int* __restrict__ YG_dt, unsigned int* __restrict__ YG_td,
    float* __restrict__ out, int n_data, int n_task, int gd) {
  __shared__ unsigned sh[32][132];
  const bool is_data = (int)blockIdx.x < gd;
  const float* x; const short *Wmnb, *Wgnb, *Wsb;
  const float *bmn, *bme, *bgn, *bge, *bs, *bias_other;
  unsigned* YG; float* out_init; int n, bid;
  if (is_data) {
    x = x_data; Wmnb = Wb; Wgnb = Wb + 16384; Wsb = Wb + 32768;
    bmn = bmn_dt; bme = bme_dt; bgn = bgn_dt; bge = bge_dt;
    bs = bs_data; bias_other = bias_td;
    YG = YG_dt; out_init = out; n = n_data; bid = blockIdx.x;
  } else {
    x = x_task; Wmnb = Wb + 3 * 16384; Wgnb = Wb + 4 * 16384; Wsb = Wb + 5 * 16384;
    bmn = bmn_td; bme = bme_td; bgn = bgn_td; bge = bge_td;
    bs = bs_task; bias_other = bias_dt;
    YG = YG_td; out_init = out + (size_t)n_data * D_DIM; n = n_task; bid = blockIdx.x - gd;
  }
  const int t = threadIdx.x;
  const int wave = t >> 6, lane = t & 63;
  const int q = lane >> 4, l15 = lane & 15;
  const int ng = wave >> 1;
  const int h = (wave & 1) * 64;
  const int base_node = bid * 32;
  const int node_base = base_node + ng * 16;

  short8 a[4];
  {
    int m = node_base + l15;
    int mc = m < n ? m : (n - 1);
    const float* xrow = x + (size_t)mc * D_DIM;
#pragma unroll
    for (int ks = 0; ks < 4; ++ks) {
      float4 f0 = *(const float4*)(xrow + ks * 32 + q * 8);
      float4 f1 = *(const float4*)(xrow + ks * 32 + q * 8 + 4);
      union { short8 s; __hip_bfloat162 hh[4]; } u;
      u.hh[0] = __float22bfloat162_rn({f0.x, f0.y});
      u.hh[1] = __float22bfloat162_rn({f0.z, f0.w});
      u.hh[2] = __float22bfloat162_rn({f1.x, f1.y});
      u.hh[3] = __float22bfloat162_rn({f1.z, f1.w});
      a[ks] = u.s;
    }
  }

  f32x4 accY[4], accG[4], accS[4];
#pragma unroll
  for (int nt = 0; nt < 4; ++nt) { accY[nt] = {0,0,0,0}; accG[nt] = {0,0,0,0}; accS[nt] = {0,0,0,0}; }

#pragma unroll
  for (int nt = 0; nt < 4; ++nt) {
    const int row = h + nt * 16 + l15;
#pragma unroll
    for (int ks = 0; ks < 4; ++ks) {
      const int off = row * D_DIM + ks * 32 + q * 8;
      short8 bm  = *(const short8*)(Wmnb + off);
      short8 bg  = *(const short8*)(Wgnb + off);
      short8 bsw = *(const short8*)(Wsb + off);
      accY[nt] = __builtin_amdgcn_mfma_f32_16x16x32_bf16(a[ks], bm,  accY[nt], 0, 0, 0);
      accG[nt] = __builtin_amdgcn_mfma_f32_16x16x32_bf16(a[ks], bg,  accG[nt], 0, 0, 0);
      accS[nt] = __builtin_amdgcn_mfma_f32_16x16x32_bf16(a[ks], bsw, accS[nt], 0, 0, 0);
    }
  }

#pragma unroll
  for (int nt = 0; nt < 4; ++nt) {
    int d = h + nt * 16 + l15;
    float bmv = bmn[d] + bme[d];
    float bgv = bgn[d] + bge[d];
#pragma unroll
    for (int r = 0; r < 4; ++r) {
      union { __hip_bfloat162 hh; unsigned u; } pck;
      pck.hh = __float22bfloat162_rn({accY[nt][r] + bmv,
                                      (accG[nt][r] + bgv) * NEG_LOG2E});
      sh[ng * 16 + q * 4 + r][d] = pck.u;
    }
  }
  __syncthreads();
#pragma unroll
  for (int it = 0; it < 4; ++it) {
    int idx = (it * 256 + t) * 4;
    int nl = idx >> 7, dd = idx & 127;
    int node = base_node + nl;
    if (node < n)
      *(uint4*)(YG + (size_t)node * D_DIM + dd) = *(const uint4*)&sh[nl][dd];
  }
  __syncthreads();

  float* shf = (float*)sh;
#pragma unroll
  for (int nt = 0; nt < 4; ++nt) {
    int d = h + nt * 16 + l15;
    float bsv = bs[d];
#pragma unroll
    for (int r = 0; r < 4; ++r)
      shf[(ng * 16 + q * 4 + r) * 132 + d] = sigmoid_fast(accS[nt][r] + bsv) + 0.5f;
  }
  __syncthreads();
#pragma unroll
  for (int it = 0; it < 4; ++it) {
    int idx = (it * 256 + t) * 4;
    int nl = idx >> 7, dd = idx & 127;
    int node = base_node + nl;
    if (node < n) {
      float4 xv = *(const float4*)(x + (size_t)node * D_DIM + dd);
      float4 bo = *(const float4*)(bias_other + dd);
      const float* sp = &shf[nl * 132 + dd];
      float4 o;
      o.x = sp[0] * xv.x + bo.x;
      o.y = sp[1] * xv.y + bo.y;
      o.z = sp[2] * xv.z + bo.z;
      o.w = sp[3] * xv.w + bo.w;
      *(float4*)(out_init + (size_t)node * D_DIM + dd) = o;
    }
  }
}

// Pass A: coarse partition, int4-vectorized. Block handles 4096 edges of each
// list; per-bucket contiguous runs reserved with one global atomicAdd.
// Entry = {src, ef_hi24|loc8}.
__global__ __launch_bounds__(256) void sort_a_kernel(
    const int* __restrict__ src_dt, const int* __restrict__ dst_dt, const float* __restrict__ ef_dt,
    const int* __restrict__ src_td, const int* __restrict__ dst_td, const float* __restrict__ ef_td,
    int* __restrict__ bcur, int2* __restrict__ eA, int nbt, int NB, int E) {
  __shared__ int lh[768];
  __shared__ int lcur[768];
  int t = threadIdx.x;
  lh[t] = 0; lh[t + 256] = 0; lh[t + 512] = 0;
  __syncthreads();
  int e0 = blockIdx.x * 4096;
  int e1 = min(E, e0 + 4096);
  const bool full = (e1 - e0 == 4096);
  if (full) {
#pragma unroll
    for (int k = 0; k < 4; ++k) {
      int b4 = e0 + (k * 256 + t) * 4;
      int4 d = *(const int4*)(dst_dt + b4);
      atomicAdd(&lh[d.x >> 6], 1); atomicAdd(&lh[d.y >> 6], 1);
      atomicAdd(&lh[d.z >> 6], 1); atomicAdd(&lh[d.w >> 6], 1);
      int4 d2 = *(const int4*)(dst_td + b4);
      atomicAdd(&lh[nbt + (d2.x >> 8)], 1); atomicAdd(&lh[nbt + (d2.y >> 8)], 1);
      atomicAdd(&lh[nbt + (d2.z >> 8)], 1); atomicAdd(&lh[nbt + (d2.w >> 8)], 1);
    }
  } else {
    for (int i = e0 + t; i < e1; i += 256) {
      atomicAdd(&lh[dst_dt[i] >> 6], 1);
      atomicAdd(&lh[nbt + (dst_td[i] >> 8)], 1);
    }
  }
  __syncthreads();
#pragma unroll
  for (int k = 0; k < 3; ++k) {
    int b = t + k * 256;
    int c = lh[b];
    if (b < NB && c) lcur[b] = atomicAdd(&bcur[b], c);
  }
  __syncthreads();
#define PUT_DT(ss, dd, ff) do { \
    int pos = atomicAdd(&lcur[(dd) >> 6], 1); \
    eA[pos] = make_int2((ss), (int)((__float_as_uint(ff) & 0xFFFFFF00u) | (unsigned)((dd) & 63))); \
  } while (0)
#define PUT_TD(ss, dd, ff) do { \
    int pos = atomicAdd(&lcur[nbt + ((dd) >> 8)], 1); \
    eA[pos] = make_int2((ss), (int)((__float_as_uint(ff) & 0xFFFFFF00u) | (unsigned)((dd) & 255))); \
  } while (0)
  if (full) {
#pragma unroll
    for (int k = 0; k < 4; ++k) {
      int b4 = e0 + (k * 256 + t) * 4;
      int4 s = *(const int4*)(src_dt + b4);
      int4 d = *(const int4*)(dst_dt + b4);
      float4 f = *(const float4*)(ef_dt + b4);
      PUT_DT(s.x, d.x, f.x); PUT_DT(s.y, d.y, f.y);
      PUT_DT(s.z, d.z, f.z); PUT_DT(s.w, d.w, f.w);
      s = *(const int4*)(src_td + b4);
      d = *(const int4*)(dst_td + b4);
      f = *(const float4*)(ef_td + b4);
      PUT_TD(s.x, d.x, f.x); PUT_TD(s.y, d.y, f.y);
      PUT_TD(s.z, d.z, f.z); PUT_TD(s.w, d.w, f.w);
    }
  } else {
    for (int i = e0 + t; i < e1; i += 256) {
      PUT_DT(src_dt[i], dst_dt[i], ef_dt[i]);
      PUT_TD(src_td[i], dst_td[i], ef_td[i]);
    }
  }
#undef PUT_DT
#undef PUT_TD
}

// Pass B: one block per bucket. 256-bin hist+scan; write final per-dst offsets;
// scatter entries to final positions (src pre-shifted <<7 for add-only gather).
__global__ __launch_bounds__(256) void sort_b_kernel(
    const int2* __restrict__ eA, const int* __restrict__ bbase,
    int* __restrict__ offsets, int2* __restrict__ eB,
    int nbt, int n_task, int n_tot) {
  __shared__ int lh[256], sc[256], lcur[256];
  int b = blockIdx.x, t = threadIdx.x;
  int base = bbase[b];
  int cnt = bbase[b + 1] - base;
  int c0, nloc;
  if (b < nbt) { c0 = b << 6; nloc = min(64, n_task - c0); }
  else { c0 = n_task + ((b - nbt) << 8); nloc = min(256, n_tot - c0); }
  lh[t] = 0; __syncthreads();
  for (int i = base + t; i < base + cnt; i += 256)
    atomicAdd(&lh[((unsigned)eA[i].y) & 255u], 1);
  __syncthreads();
  int v = lh[t];
  sc[t] = v; __syncthreads();
  for (int s = 1; s < 256; s <<= 1) {
    int u = (t >= s) ? sc[t - s] : 0;
    __syncthreads(); sc[t] += u; __syncthreads();
  }
  int ex = sc[t] - v;
  lcur[t] = base + ex;
  if (t < nloc) offsets[c0 + t] = base + ex;
  __syncthreads();
  for (int i = base + t; i < base + cnt; i += 256) {
    int2 e = eA[i];
    int pos = atomicAdd(&lcur[((unsigned)e.y) & 255u], 1);
    eB[pos] = make_int2(e.x << 7, e.y);
  }
}

// Per-type gather: one wave per dst node. eB.x is pre-shifted src*128;
// G channel pre-scaled by -log2e.
__device__ __forceinline__ void gs(float2& acc, int2 e, uint2 yv,
                                   float2 wme, float2 wge2) {
  float f = __int_as_float(e.y & (int)0xFFFFFF00);
  float g0 = __builtin_amdgcn_rcpf(1.0f + __builtin_amdgcn_exp2f(fmaf(f, wge2.x, bf_hi(yv.x)))) - 0.5f;
  float g1 = __builtin_amdgcn_rcpf(1.0f + __builtin_amdgcn_exp2f(fmaf(f, wge2.y, bf_hi(yv.y)))) - 0.5f;
  acc.x = fmaf(fmaf(f, wme.x, bf_lo(yv.x)), g0, acc.x);
  acc.y = fmaf(fmaf(f, wme.y, bf_lo(yv.y)), g1, acc.y);
}

__global__ __launch_bounds__(256) void gather_one_kernel(
    const unsigned* __restrict__ YG,
    const int* __restrict__ offsets, const int2* __restrict__ edata,
    const float* __restrict__ Wme, const float* __restrict__ Wge,
    float* __restrict__ outp, int n) {
  int w = (int)((blockIdx.x * 256u + threadIdx.x) >> 6);
  int lane = threadIdx.x & 63;
  if (w >= n) return;
  int beg = __builtin_amdgcn_readfirstlane(offsets[w]);
  int end = __builtin_amdgcn_readfirstlane(offsets[w + 1]);
  float2 wme = *(const float2*)(Wme + 2 * lane);
  float2 wge = *(const float2*)(Wge + 2 * lane);
  float2 wge2 = {wge.x * NEG_LOG2E, wge.y * NEG_LOG2E};
  const unsigned* YGl = YG + 2 * lane;
  float* op = outp + (size_t)w * D_DIM + 2 * lane;
  float2 acc0 = *(const float2*)op;
  float2 acc1 = {0.0f, 0.0f};
  int p = beg;
  for (; p + 8 <= end; p += 8) {
    int2 e0 = edata[p],     e1 = edata[p + 1], e2 = edata[p + 2], e3 = edata[p + 3];
    int2 e4 = edata[p + 4], e5 = edata[p + 5], e6 = edata[p + 6], e7 = edata[p + 7];
    gs(acc0, e0, *(const uint2*)(YGl + e0.x), wme, wge2);
    gs(acc1, e1, *(const uint2*)(YGl + e1.x), wme, wge2);
    gs(acc0, e2, *(const uint2*)(YGl + e2.x), wme, wge2);
    gs(acc1, e3, *(const uint2*)(YGl + e3.x), wme, wge2);
    gs(acc0, e4, *(const uint2*)(YGl + e4.x), wme, wge2);
    gs(acc1, e5, *(const uint2*)(YGl + e5.x), wme, wge2);
    gs(acc0, e6, *(const uint2*)(YGl + e6.x), wme, wge2);
    gs(acc1, e7, *(const uint2*)(YGl + e7.x), wme, wge2);
  }
  for (; p + 2 <= end; p += 2) {
    int2 e0 = edata[p], e1 = edata[p + 1];
    gs(acc0, e0, *(const uint2*)(YGl + e0.x), wme, wge2);
    gs(acc1, e1, *(const uint2*)(YGl + e1.x), wme, wge2);
  }
  if (p < end) {
    int2 e0 = edata[p];
    gs(acc0, e0, *(const uint2*)(YGl + e0.x), wme, wge2);
  }
  acc0.x = fmaxf(acc0.x + acc1.x, 0.0f);
  acc0.y = fmaxf(acc0.y + acc1.y, 0.0f);
  *(float2*)op = acc0;
}

extern "C" void kernel_launch(void* const* d_in, const int* in_sizes, int n_in,
                              void* d_out, int out_size, void* d_ws, size_t ws_size,
                              hipStream_t stream) {
  const float* x_data  = (const float*)d_in[0];
  const float* x_task  = (const float*)d_in[1];
  const int*   src_dt  = (const int*)d_in[2];
  const int*   dst_dt  = (const int*)d_in[3];
  const float* ef_dt   = (const float*)d_in[4];
  const int*   src_td  = (const int*)d_in[5];
  const int*   dst_td  = (const int*)d_in[6];
  const float* ef_td   = (const float*)d_in[7];
  const float* Wmn_dt  = (const float*)d_in[8];
  const float* bmn_dt  = (const float*)d_in[9];
  const float* Wme_dt  = (const float*)d_in[10];
  const float* bme_dt  = (const float*)d_in[11];
  const float* Wgn_dt  = (const float*)d_in[12];
  const float* bgn_dt  = (const float*)d_in[13];
  const float* Wge_dt  = (const float*)d_in[14];
  const float* bge_dt  = (const float*)d_in[15];
  const float* bias_dt = (const float*)d_in[16];
  const float* Wmn_td  = (const float*)d_in[17];
  const float* bmn_td  = (const float*)d_in[18];
  const float* Wme_td  = (const float*)d_in[19];
  const float* bme_td  = (const float*)d_in[20];
  const float* Wgn_td  = (const float*)d_in[21];
  const float* bgn_td  = (const float*)d_in[22];
  const float* Wge_td  = (const float*)d_in[23];
  const float* bge_td  = (const float*)d_in[24];
  const float* bias_td = (const float*)d_in[25];
  const float* Ws_data = (const float*)d_in[26];
  const float* bs_data = (const float*)d_in[27];
  const float* Ws_task = (const float*)d_in[28];
  const float* bs_task = (const float*)d_in[29];
  float* out = (float*)d_out;

  const int N_DATA = in_sizes[0] / D_DIM;   // 100000
  const int N_TASK = in_sizes[1] / D_DIM;   // 20000
  const int E = in_sizes[2];                // 1000000
  const int N_TOT = N_TASK + N_DATA;
  const int NBT = (N_TASK + 63) >> 6;       // 313 task buckets (64 dsts each)
  const int NBD = (N_DATA + 255) >> 8;      // 391 data buckets (256 dsts each)
  const int NB = NBT + NBD;                 // 704
  const int GD = (N_DATA + 31) / 32;
  const int GT = (N_TASK + 31) / 32;

  char* ws = (char*)d_ws;
  size_t off = 0;
  auto alloc = [&](size_t bytes) { void* p = ws + off; off += (bytes + 255) & ~(size_t)255; return p; };
  unsigned int* YG_dt = (unsigned int*)alloc((size_t)N_DATA * D_DIM * 4);
  unsigned int* YG_td = (unsigned int*)alloc((size_t)N_TASK * D_DIM * 4);
  int2* eA     = (int2*)alloc((size_t)2 * E * 8);
  int2* eB     = (int2*)alloc((size_t)2 * E * 8);
  int*  offs   = (int*)alloc((size_t)(N_TOT + 1) * 4);
  int*  ghist  = (int*)alloc(1024 * 4);     // 768 hist + done counter
  int*  bbase  = (int*)alloc(768 * 4);
  int*  bcur   = (int*)alloc(768 * 4);
  short* Wb    = (short*)alloc((size_t)6 * 16384 * 2);
  (void)ws_size; (void)n_in; (void)out_size;

  hipMemsetAsync(ghist, 0, 1024 * 4, stream);

  fused_pre_kernel<<<256, 256, 0, stream>>>(
      Wmn_dt, Wgn_dt, Ws_data, Wmn_td, Wgn_td, Ws_task, Wb,
      dst_dt, dst_td, ghist, ghist + 768, bbase, bcur, offs,
      NBT, NB, E, N_TOT);

  node_mfma_all<<<GD + GT, 256, 0, stream>>>(
      x_data, x_task, Wb,
      bmn_dt, bme_dt, bgn_dt, bge_dt,
      bmn_td, bme_td, bgn_td, bge_td,
      bs_data, bs_task, bias_dt, bias_td,
      YG_dt, YG_td, out, N_DATA, N_TASK, GD);

  sort_a_kernel<<<(E + 4095) / 4096, 256, 0, stream>>>(
      src_dt, dst_dt, ef_dt, src_td, dst_td, ef_td, bcur, eA, NBT, NB, E);
  sort_b_kernel<<<NB, 256, 0, stream>>>(eA, bbase, offs, eB, NBT, N_TASK, N_TOT);

  // task-dst gather (dt conv): output rows n_data..n_tot-1, offsets[0..n_task]
  gather_one_kernel<<<(N_TASK + 3) / 4, 256, 0, stream>>>(
      YG_dt, offs, eB, Wme_dt, Wge_dt, out + (size_t)N_DATA * D_DIM, N_TASK);
  // data-dst gather (td conv): output rows 0..n_data-1, offsets[n_task..n_tot]
  gather_one_kernel<<<(N_DATA + 3) / 4, 256, 0, stream>>>(
      YG_td, offs + N_TASK, eB, Wme_td, Wge_td, out, N_DATA);
}

// Round 11
// 443.335 us; speedup vs baseline: 1.2166x; 1.0718x over previous
//
#include <hip/hip_runtime.h>
#include <hip/hip_bf16.h>
#include <cstdint>
#include <cstddef>

#define D_DIM 128
#define NEG_LOG2E (-1.44269504f)

typedef __attribute__((ext_vector_type(8))) short short8;
typedef __attribute__((ext_vector_type(4))) float f32x4;

__device__ __forceinline__ float sigmoid_fast(float z) {
  return __builtin_amdgcn_rcpf(1.0f + __expf(-z));
}

__device__ __forceinline__ unsigned short f2bf(float f) {
  union { float f; unsigned u; } v; v.f = f;
  unsigned r = v.u + 0x7FFF + ((v.u >> 16) & 1);   // RNE
  return (unsigned short)(r >> 16);
}
__device__ __forceinline__ float bf_lo(unsigned u) { return __uint_as_float(u << 16); }
__device__ __forceinline__ float bf_hi(unsigned u) { return __uint_as_float(u & 0xFFFF0000u); }

// Fused: wconv (blocks 0..95, FRAGMENT-MAJOR output) + coarse histogram
// (all blocks, int4) + bucket scan (last block, device-scope done-counter).
// Fragment order: element (row,col) of matrix mat -> rb=row>>4, l15=row&15,
// ks=col>>5, q=(col&31)>>3, el=col&7, lane=l15+16q, stored at
// mat*16384 + ((rb*4+ks)*64 + lane)*8 + el. node_mfma reads lane-contiguous.
__global__ __launch_bounds__(256) void fused_pre_kernel(
    const float* __restrict__ s0, const float* __restrict__ s1, const float* __restrict__ s2,
    const float* __restrict__ s3, const float* __restrict__ s4, const float* __restrict__ s5,
    short* __restrict__ wdst,
    const int* __restrict__ dst_dt, const int* __restrict__ dst_td,
    int* __restrict__ ghist, int* __restrict__ done,
    int* __restrict__ bbase, int* __restrict__ bcur, int* __restrict__ offsets,
    int nbt, int NB, int E, int n_tot) {
  __shared__ int lh[768];
  __shared__ int sc[256];
  __shared__ int lastflag;
  int t = threadIdx.x;

  // --- weight bf16 conversion, fragment-major ---
  if (blockIdx.x < 96) {
    int idx = blockIdx.x * 256 + t;
    int mat = idx >> 12;
    int pos = (idx & 4095) * 4;
    const float* s = (mat == 0) ? s0 : (mat == 1) ? s1 : (mat == 2) ? s2
                   : (mat == 3) ? s3 : (mat == 4) ? s4 : s5;
    float4 f = *(const float4*)(s + pos);
    short4 o;
    o.x = (short)f2bf(f.x); o.y = (short)f2bf(f.y);
    o.z = (short)f2bf(f.z); o.w = (short)f2bf(f.w);
    int row = pos >> 7, col = pos & 127;
    int rb = row >> 4, l15 = row & 15;
    int ks = col >> 5, q = (col & 31) >> 3, el = col & 7;
    int lane = l15 + (q << 4);
    int off = mat * 16384 + ((((rb << 2) + ks) << 6) + lane) * 8 + el;
    *(short4*)(wdst + off) = o;
  }

  // --- coarse histogram with LDS pre-aggregation (int4 loads) ---
  lh[t] = 0; lh[t + 256] = 0; lh[t + 512] = 0;
  __syncthreads();
  int E4 = E >> 2;
  for (int i = blockIdx.x * 256 + t; i < E4; i += gridDim.x * 256) {
    int4 a = *(const int4*)(dst_dt + 4 * i);
    atomicAdd(&lh[a.x >> 6], 1); atomicAdd(&lh[a.y >> 6], 1);
    atomicAdd(&lh[a.z >> 6], 1); atomicAdd(&lh[a.w >> 6], 1);
    int4 b = *(const int4*)(dst_td + 4 * i);
    atomicAdd(&lh[nbt + (b.x >> 8)], 1); atomicAdd(&lh[nbt + (b.y >> 8)], 1);
    atomicAdd(&lh[nbt + (b.z >> 8)], 1); atomicAdd(&lh[nbt + (b.w >> 8)], 1);
  }
  if (blockIdx.x == 0 && t < (E & 3)) {
    int j = (E & ~3) + t;
    atomicAdd(&lh[dst_dt[j] >> 6], 1);
    atomicAdd(&lh[nbt + (dst_td[j] >> 8)], 1);
  }
  __syncthreads();
#pragma unroll
  for (int k = 0; k < 3; ++k) {
    int b = t + k * 256;
    int c = lh[b];
    if (b < NB && c) atomicAdd(&ghist[b], c);
  }
  __threadfence();
  __syncthreads();
  if (t == 0) {
    int prev = atomicAdd(done, 1);
    lastflag = (prev == (int)gridDim.x - 1);
  }
  __syncthreads();
  if (!lastflag) return;
  __threadfence();

  // --- bucket scan (single block) ---
  int i0 = t * 3;
  int c0 = (i0     < NB) ? atomicAdd(&ghist[i0],     0) : 0;
  int c1 = (i0 + 1 < NB) ? atomicAdd(&ghist[i0 + 1], 0) : 0;
  int c2 = (i0 + 2 < NB) ? atomicAdd(&ghist[i0 + 2], 0) : 0;
  int tot = c0 + c1 + c2;
  sc[t] = tot; __syncthreads();
  for (int s = 1; s < 256; s <<= 1) {
    int u = (t >= s) ? sc[t - s] : 0;
    __syncthreads(); sc[t] += u; __syncthreads();
  }
  int base = sc[t] - tot;
  if (i0     < NB) { bbase[i0]     = base;           bcur[i0]     = base; }
  if (i0 + 1 < NB) { bbase[i0 + 1] = base + c0;      bcur[i0 + 1] = base + c0; }
  if (i0 + 2 < NB) { bbase[i0 + 2] = base + c0 + c1; bcur[i0 + 2] = base + c0 + c1; }
  if (t == 255) { bbase[NB] = sc[255]; offsets[n_tot] = sc[255]; }
}

// Per-node MFMA precompute, 64 nodes/block, 512 threads (8 waves:
// 4 node-groups x 2 h-halves). Weights read coalesced from fragment-major Wb.
// G channel of YG pre-scaled by -log2e.
__global__ __launch_bounds__(512) void node_mfma_all(
    const float* __restrict__ x_data, const float* __restrict__ x_task,
    const short* __restrict__ Wb,
    const float* __restrict__ bmn_dt, const float* __restrict__ bme_dt,
    const float* __restrict__ bgn_dt, const float* __restrict__ bge_dt,
    const float* __restrict__ bmn_td, const float* __restrict__ bme_td,
    const float* __restrict__ bgn_td, const float* __restrict__ bge_td,
    const float* __restrict__ bs_data, const float* __restrict__ bs_task,
    const float* __restrict__ bias_dt, const float* __restrict__ bias_td,
    unsigned int* __restrict__ YG_dt, unsigned int* __restrict__ YG_td,
    float* __restrict__ out, int n_data, int n_task, int gd) {
  __shared__ unsigned sh[64][132];
  const bool is_data = (int)blockIdx.x < gd;
  const float* x; const short *Wmnb, *Wgnb, *Wsb;
  const float *bmn, *bme, *bgn, *bge, *bs, *bias_other;
  unsigned* YG; float* out_init; int n, bid;
  if (is_data) {
    x = x_data; Wmnb = Wb; Wgnb = Wb + 16384; Wsb = Wb + 32768;
    bmn = bmn_dt; bme = bme_dt; bgn = bgn_dt; bge = bge_dt;
    bs = bs_data; bias_other = bias_td;
    YG = YG_dt; out_init = out; n = n_data; bid = blockIdx.x;
  } else {
    x = x_task; Wmnb = Wb + 3 * 16384; Wgnb = Wb + 4 * 16384; Wsb = Wb + 5 * 16384;
    bmn = bmn_td; bme = bme_td; bgn = bgn_td; bge = bge_td;
    bs = bs_task; bias_other = bias_dt;
    YG = YG_td; out_init = out + (size_t)n_data * D_DIM; n = n_task; bid = blockIdx.x - gd;
  }
  const int t = threadIdx.x;
  const int wave = t >> 6, lane = t & 63;
  const int q = lane >> 4, l15 = lane & 15;
  const int ng = wave >> 1;                 // 0..3: 16-node group
  const int h = (wave & 1) * 64;            // output-dim half
  const int rb4 = (wave & 1) << 2;          // row-block base = h/16
  const int base_node = bid * 64;
  const int node_base = base_node + ng * 16;

  short8 a[4];
  {
    int m = node_base + l15;
    int mc = m < n ? m : (n - 1);
    const float* xrow = x + (size_t)mc * D_DIM;
#pragma unroll
    for (int ks = 0; ks < 4; ++ks) {
      float4 f0 = *(const float4*)(xrow + ks * 32 + q * 8);
      float4 f1 = *(const float4*)(xrow + ks * 32 + q * 8 + 4);
      union { short8 s; __hip_bfloat162 hh[4]; } u;
      u.hh[0] = __float22bfloat162_rn({f0.x, f0.y});
      u.hh[1] = __float22bfloat162_rn({f0.z, f0.w});
      u.hh[2] = __float22bfloat162_rn({f1.x, f1.y});
      u.hh[3] = __float22bfloat162_rn({f1.z, f1.w});
      a[ks] = u.s;
    }
  }

  f32x4 accY[4], accG[4], accS[4];
#pragma unroll
  for (int nt = 0; nt < 4; ++nt) { accY[nt] = {0,0,0,0}; accG[nt] = {0,0,0,0}; accS[nt] = {0,0,0,0}; }

#pragma unroll
  for (int nt = 0; nt < 4; ++nt) {
    const int rb = rb4 + nt;
#pragma unroll
    for (int ks = 0; ks < 4; ++ks) {
      const int woff = ((((rb << 2) + ks) << 6) << 3) + (lane << 3);  // ((rb*4+ks)*64+lane)*8
      short8 bm  = *(const short8*)(Wmnb + woff);
      short8 bg  = *(const short8*)(Wgnb + woff);
      short8 bsw = *(const short8*)(Wsb + woff);
      accY[nt] = __builtin_amdgcn_mfma_f32_16x16x32_bf16(a[ks], bm,  accY[nt], 0, 0, 0);
      accG[nt] = __builtin_amdgcn_mfma_f32_16x16x32_bf16(a[ks], bg,  accG[nt], 0, 0, 0);
      accS[nt] = __builtin_amdgcn_mfma_f32_16x16x32_bf16(a[ks], bsw, accS[nt], 0, 0, 0);
    }
  }

#pragma unroll
  for (int nt = 0; nt < 4; ++nt) {
    int d = h + nt * 16 + l15;
    float bmv = bmn[d] + bme[d];
    float bgv = bgn[d] + bge[d];
#pragma unroll
    for (int r = 0; r < 4; ++r) {
      union { __hip_bfloat162 hh; unsigned u; } pck;
      pck.hh = __float22bfloat162_rn({accY[nt][r] + bmv,
                                      (accG[nt][r] + bgv) * NEG_LOG2E});
      sh[ng * 16 + q * 4 + r][d] = pck.u;
    }
  }
  __syncthreads();
#pragma unroll
  for (int it = 0; it < 4; ++it) {
    int idx = (it * 512 + t) * 4;
    int nl = idx >> 7, dd = idx & 127;
    int node = base_node + nl;
    if (node < n)
      *(uint4*)(YG + (size_t)node * D_DIM + dd) = *(const uint4*)&sh[nl][dd];
  }
  __syncthreads();

  float* shf = (float*)sh;
#pragma unroll
  for (int nt = 0; nt < 4; ++nt) {
    int d = h + nt * 16 + l15;
    float bsv = bs[d];
#pragma unroll
    for (int r = 0; r < 4; ++r)
      shf[(ng * 16 + q * 4 + r) * 132 + d] = sigmoid_fast(accS[nt][r] + bsv) + 0.5f;
  }
  __syncthreads();
#pragma unroll
  for (int it = 0; it < 4; ++it) {
    int idx = (it * 512 + t) * 4;
    int nl = idx >> 7, dd = idx & 127;
    int node = base_node + nl;
    if (node < n) {
      float4 xv = *(const float4*)(x + (size_t)node * D_DIM + dd);
      float4 bo = *(const float4*)(bias_other + dd);
      const float* sp = &shf[nl * 132 + dd];
      float4 o;
      o.x = sp[0] * xv.x + bo.x;
      o.y = sp[1] * xv.y + bo.y;
      o.z = sp[2] * xv.z + bo.z;
      o.w = sp[3] * xv.w + bo.w;
      *(float4*)(out_init + (size_t)node * D_DIM + dd) = o;
    }
  }
}

// Pass A: coarse partition, int4-vectorized. Block handles 4096 edges of each
// list; per-bucket contiguous runs reserved with one global atomicAdd.
// Entry = {src, ef_hi24|loc8}.
__global__ __launch_bounds__(256) void sort_a_kernel(
    const int* __restrict__ src_dt, const int* __restrict__ dst_dt, const float* __restrict__ ef_dt,
    const int* __restrict__ src_td, const int* __restrict__ dst_td, const float* __restrict__ ef_td,
    int* __restrict__ bcur, int2* __restrict__ eA, int nbt, int NB, int E) {
  __shared__ int lh[768];
  __shared__ int lcur[768];
  int t = threadIdx.x;
  lh[t] = 0; lh[t + 256] = 0; lh[t + 512] = 0;
  __syncthreads();
  int e0 = blockIdx.x * 4096;
  int e1 = min(E, e0 + 4096);
  const bool full = (e1 - e0 == 4096);
  if (full) {
#pragma unroll
    for (int k = 0; k < 4; ++k) {
      int b4 = e0 + (k * 256 + t) * 4;
      int4 d = *(const int4*)(dst_dt + b4);
      atomicAdd(&lh[d.x >> 6], 1); atomicAdd(&lh[d.y >> 6], 1);
      atomicAdd(&lh[d.z >> 6], 1); atomicAdd(&lh[d.w >> 6], 1);
      int4 d2 = *(const int4*)(dst_td + b4);
      atomicAdd(&lh[nbt + (d2.x >> 8)], 1); atomicAdd(&lh[nbt + (d2.y >> 8)], 1);
      atomicAdd(&lh[nbt + (d2.z >> 8)], 1); atomicAdd(&lh[nbt + (d2.w >> 8)], 1);
    }
  } else {
    for (int i = e0 + t; i < e1; i += 256) {
      atomicAdd(&lh[dst_dt[i] >> 6], 1);
      atomicAdd(&lh[nbt + (dst_td[i] >> 8)], 1);
    }
  }
  __syncthreads();
#pragma unroll
  for (int k = 0; k < 3; ++k) {
    int b = t + k * 256;
    int c = lh[b];
    if (b < NB && c) lcur[b] = atomicAdd(&bcur[b], c);
  }
  __syncthreads();
#define PUT_DT(ss, dd, ff) do { \
    int pos = atomicAdd(&lcur[(dd) >> 6], 1); \
    eA[pos] = make_int2((ss), (int)((__float_as_uint(ff) & 0xFFFFFF00u) | (unsigned)((dd) & 63))); \
  } while (0)
#define PUT_TD(ss, dd, ff) do { \
    int pos = atomicAdd(&lcur[nbt + ((dd) >> 8)], 1); \
    eA[pos] = make_int2((ss), (int)((__float_as_uint(ff) & 0xFFFFFF00u) | (unsigned)((dd) & 255))); \
  } while (0)
  if (full) {
#pragma unroll
    for (int k = 0; k < 4; ++k) {
      int b4 = e0 + (k * 256 + t) * 4;
      int4 s = *(const int4*)(src_dt + b4);
      int4 d = *(const int4*)(dst_dt + b4);
      float4 f = *(const float4*)(ef_dt + b4);
      PUT_DT(s.x, d.x, f.x); PUT_DT(s.y, d.y, f.y);
      PUT_DT(s.z, d.z, f.z); PUT_DT(s.w, d.w, f.w);
      s = *(const int4*)(src_td + b4);
      d = *(const int4*)(dst_td + b4);
      f = *(const float4*)(ef_td + b4);
      PUT_TD(s.x, d.x, f.x); PUT_TD(s.y, d.y, f.y);
      PUT_TD(s.z, d.z, f.z); PUT_TD(s.w, d.w, f.w);
    }
  } else {
    for (int i = e0 + t; i < e1; i += 256) {
      PUT_DT(src_dt[i], dst_dt[i], ef_dt[i]);
      PUT_TD(src_td[i], dst_td[i], ef_td[i]);
    }
  }
#undef PUT_DT
#undef PUT_TD
}

// Pass B: one block per bucket. 256-bin hist+scan; write final per-dst offsets;
// scatter entries to final positions (src pre-shifted <<7 for add-only gather).
__global__ __launch_bounds__(256) void sort_b_kernel(
    const int2* __restrict__ eA, const int* __restrict__ bbase,
    int* __restrict__ offsets, int2* __restrict__ eB,
    int nbt, int n_task, int n_tot) {
  __shared__ int lh[256], sc[256], lcur[256];
  int b = blockIdx.x, t = threadIdx.x;
  int base = bbase[b];
  int cnt = bbase[b + 1] - base;
  int c0, nloc;
  if (b < nbt) { c0 = b << 6; nloc = min(64, n_task - c0); }
  else { c0 = n_task + ((b - nbt) << 8); nloc = min(256, n_tot - c0); }
  lh[t] = 0; __syncthreads();
  for (int i = base + t; i < base + cnt; i += 256)
    atomicAdd(&lh[((unsigned)eA[i].y) & 255u], 1);
  __syncthreads();
  int v = lh[t];
  sc[t] = v; __syncthreads();
  for (int s = 1; s < 256; s <<= 1) {
    int u = (t >= s) ? sc[t - s] : 0;
    __syncthreads(); sc[t] += u; __syncthreads();
  }
  int ex = sc[t] - v;
  lcur[t] = base + ex;
  if (t < nloc) offsets[c0 + t] = base + ex;
  __syncthreads();
  for (int i = base + t; i < base + cnt; i += 256) {
    int2 e = eA[i];
    int pos = atomicAdd(&lcur[((unsigned)e.y) & 255u], 1);
    eB[pos] = make_int2(e.x << 7, e.y);
  }
}

// Per-type gather: one wave per dst node. eB.x is pre-shifted src*128;
// G channel pre-scaled by -log2e.
__device__ __forceinline__ void gs(float2& acc, int2 e, uint2 yv,
                                   float2 wme, float2 wge2) {
  float f = __int_as_float(e.y & (int)0xFFFFFF00);
  float g0 = __builtin_amdgcn_rcpf(1.0f + __builtin_amdgcn_exp2f(fmaf(f, wge2.x, bf_hi(yv.x)))) - 0.5f;
  float g1 = __builtin_amdgcn_rcpf(1.0f + __builtin_amdgcn_exp2f(fmaf(f, wge2.y, bf_hi(yv.y)))) - 0.5f;
  acc.x = fmaf(fmaf(f, wme.x, bf_lo(yv.x)), g0, acc.x);
  acc.y = fmaf(fmaf(f, wme.y, bf_lo(yv.y)), g1, acc.y);
}

__global__ __launch_bounds__(256) void gather_one_kernel(
    const unsigned* __restrict__ YG,
    const int* __restrict__ offsets, const int2* __restrict__ edata,
    const float* __restrict__ Wme, const float* __restrict__ Wge,
    float* __restrict__ outp, int n) {
  int w = (int)((blockIdx.x * 256u + threadIdx.x) >> 6);
  int lane = threadIdx.x & 63;
  if (w >= n) return;
  int beg = __builtin_amdgcn_readfirstlane(offsets[w]);
  int end = __builtin_amdgcn_readfirstlane(offsets[w + 1]);
  float2 wme = *(const float2*)(Wme + 2 * lane);
  float2 wge = *(const float2*)(Wge + 2 * lane);
  float2 wge2 = {wge.x * NEG_LOG2E, wge.y * NEG_LOG2E};
  const unsigned* YGl = YG + 2 * lane;
  float* op = outp + (size_t)w * D_DIM + 2 * lane;
  float2 acc0 = *(const float2*)op;
  float2 acc1 = {0.0f, 0.0f};
  int p = beg;
  for (; p + 8 <= end; p += 8) {
    int2 e0 = edata[p],     e1 = edata[p + 1], e2 = edata[p + 2], e3 = edata[p + 3];
    int2 e4 = edata[p + 4], e5 = edata[p + 5], e6 = edata[p + 6], e7 = edata[p + 7];
    gs(acc0, e0, *(const uint2*)(YGl + e0.x), wme, wge2);
    gs(acc1, e1, *(const uint2*)(YGl + e1.x), wme, wge2);
    gs(acc0, e2, *(const uint2*)(YGl + e2.x), wme, wge2);
    gs(acc1, e3, *(const uint2*)(YGl + e3.x), wme, wge2);
    gs(acc0, e4, *(const uint2*)(YGl + e4.x), wme, wge2);
    gs(acc1, e5, *(const uint2*)(YGl + e5.x), wme, wge2);
    gs(acc0, e6, *(const uint2*)(YGl + e6.x), wme, wge2);
    gs(acc1, e7, *(const uint2*)(YGl + e7.x), wme, wge2);
  }
  for (; p + 2 <= end; p += 2) {
    int2 e0 = edata[p], e1 = edata[p + 1];
    gs(acc0, e0, *(const uint2*)(YGl + e0.x), wme, wge2);
    gs(acc1, e1, *(const uint2*)(YGl + e1.x), wme, wge2);
  }
  if (p < end) {
    int2 e0 = edata[p];
    gs(acc0, e0, *(const uint2*)(YGl + e0.x), wme, wge2);
  }
  acc0.x = fmaxf(acc0.x + acc1.x, 0.0f);
  acc0.y = fmaxf(acc0.y + acc1.y, 0.0f);
  *(float2*)op = acc0;
}

extern "C" void kernel_launch(void* const* d_in, const int* in_sizes, int n_in,
                              void* d_out, int out_size, void* d_ws, size_t ws_size,
                              hipStream_t stream) {
  const float* x_data  = (const float*)d_in[0];
  const float* x_task  = (const float*)d_in[1];
  const int*   src_dt  = (const int*)d_in[2];
  const int*   dst_dt  = (const int*)d_in[3];
  const float* ef_dt   = (const float*)d_in[4];
  const int*   src_td  = (const int*)d_in[5];
  const int*   dst_td  = (const int*)d_in[6];
  const float* ef_td   = (const float*)d_in[7];
  const float* Wmn_dt  = (const float*)d_in[8];
  const float* bmn_dt  = (const float*)d_in[9];
  const float* Wme_dt  = (const float*)d_in[10];
  const float* bme_dt  = (const float*)d_in[11];
  const float* Wgn_dt  = (const float*)d_in[12];
  const float* bgn_dt  = (const float*)d_in[13];
  const float* Wge_dt  = (const float*)d_in[14];
  const float* bge_dt  = (const float*)d_in[15];
  const float* bias_dt = (const float*)d_in[16];
  const float* Wmn_td  = (const float*)d_in[17];
  const float* bmn_td  = (const float*)d_in[18];
  const float* Wme_td  = (const float*)d_in[19];
  const float* bme_td  = (const float*)d_in[20];
  const float* Wgn_td  = (const float*)d_in[21];
  const float* bgn_td  = (const float*)d_in[22];
  const float* Wge_td  = (const float*)d_in[23];
  const float* bge_td  = (const float*)d_in[24];
  const float* bias_td = (const float*)d_in[25];
  const float* Ws_data = (const float*)d_in[26];
  const float* bs_data = (const float*)d_in[27];
  const float* Ws_task = (const float*)d_in[28];
  const float* bs_task = (const float*)d_in[29];
  float* out = (float*)d_out;

  const int N_DATA = in_sizes[0] / D_DIM;   // 100000
  const int N_TASK = in_sizes[1] / D_DIM;   // 20000
  const int E = in_sizes[2];                // 1000000
  const int N_TOT = N_TASK + N_DATA;
  const int NBT = (N_TASK + 63) >> 6;       // 313 task buckets (64 dsts each)
  const int NBD = (N_DATA + 255) >> 8;      // 391 data buckets (256 dsts each)
  const int NB = NBT + NBD;                 // 704
  const int GD = (N_DATA + 63) / 64;        // 64 nodes/block now
  const int GT = (N_TASK + 63) / 64;

  char* ws = (char*)d_ws;
  size_t off = 0;
  auto alloc = [&](size_t bytes) { void* p = ws + off; off += (bytes + 255) & ~(size_t)255; return p; };
  unsigned int* YG_dt = (unsigned int*)alloc((size_t)N_DATA * D_DIM * 4);
  unsigned int* YG_td = (unsigned int*)alloc((size_t)N_TASK * D_DIM * 4);
  int2* eA     = (int2*)alloc((size_t)2 * E * 8);
  int2* eB     = (int2*)alloc((size_t)2 * E * 8);
  int*  offs   = (int*)alloc((size_t)(N_TOT + 1) * 4);
  int*  ghist  = (int*)alloc(1024 * 4);     // 768 hist + done counter
  int*  bbase  = (int*)alloc(768 * 4);
  int*  bcur   = (int*)alloc(768 * 4);
  short* Wb    = (short*)alloc((size_t)6 * 16384 * 2);
  (void)ws_size; (void)n_in; (void)out_size;

  hipMemsetAsync(ghist, 0, 1024 * 4, stream);

  fused_pre_kernel<<<256, 256, 0, stream>>>(
      Wmn_dt, Wgn_dt, Ws_data, Wmn_td, Wgn_td, Ws_task, Wb,
      dst_dt, dst_td, ghist, ghist + 768, bbase, bcur, offs,
      NBT, NB, E, N_TOT);

  node_mfma_all<<<GD + GT, 512, 0, stream>>>(
      x_data, x_task, Wb,
      bmn_dt, bme_dt, bgn_dt, bge_dt,
      bmn_td, bme_td, bgn_td, bge_td,
      bs_data, bs_task, bias_dt, bias_td,
      YG_dt, YG_td, out, N_DATA, N_TASK, GD);

  sort_a_kernel<<<(E + 4095) / 4096, 256, 0, stream>>>(
      src_dt, dst_dt, ef_dt, src_td, dst_td, ef_td, bcur, eA, NBT, NB, E);
  sort_b_kernel<<<NB, 256, 0, stream>>>(eA, bbase, offs, eB, NBT, N_TASK, N_TOT);

  // task-dst gather (dt conv): output rows n_data..n_tot-1, offsets[0..n_task]
  gather_one_kernel<<<(N_TASK + 3) / 4, 256, 0, stream>>>(
      YG_dt, offs, eB, Wme_dt, Wge_dt, out + (size_t)N_DATA * D_DIM, N_TASK);
  // data-dst gather (td conv): output rows 0..n_data-1, offsets[n_task..n_tot]
  gather_one_kernel<<<(N_DATA + 3) / 4, 256, 0, stream>>>(
      YG_td, offs + N_TASK, eB, Wme_td, Wge_td, out, N_DATA);
}